// Round 1
// baseline (2124.419 us; speedup 1.0000x reference)
//
#include <hip/hip_runtime.h>

#define N_SEQ 250000
#define LSEQ  40
#define CIN   20
#define KW    4
#define DCH   32
#define L1    37   // LSEQ - KW + 1
#define L2    34   // L1 - KW + 1
#define N_BAGS 100
#define SPB   2500
#define S_BLK 8
#define NTHR  512
#define R1    (S_BLK * L1)   // 296 conv1 output rows / block
#define R2    (S_BLK * L2)   // 272 conv2 output rows / block
#define T1C   10             // ceil(296/32) tiles of 32 rows
#define T2C   9              // ceil(272/32)
#define H1S   36             // h1 LDS row stride (f16): 72 B -> b64-aligned, 2-way-free banks

typedef _Float16 f16;
typedef _Float16 f16x8 __attribute__((ext_vector_type(8)));
typedef _Float16 f16x4 __attribute__((ext_vector_type(4)));
typedef float    f32x16 __attribute__((ext_vector_type(16)));

__device__ __forceinline__ float selu_f(float x) {
  float e = 1.6732632423543772f * (__expf(x) - 1.0f);
  return 1.0507009873554805f * ((x > 0.0f) ? x : e);
}

// ---- prep: transpose+convert weights once per launch (1 block, ~2 us) ----
__global__ __launch_bounds__(256) void prep_kernel(
    const float* __restrict__ w1, const float* __restrict__ w2,
    const float* __restrict__ aw1, const float* __restrict__ aw2,
    f16* __restrict__ w1T, f16* __restrict__ w2T,
    float* __restrict__ aw1T, float* __restrict__ aw2T)
{
  const int tid = threadIdx.x;
  for (int i = tid; i < 32 * 80; i += 256) {
    const int n = i / 80, k = i - n * 80;
    w1T[i] = (f16)w1[k * 32 + n];
  }
  for (int i = tid; i < 32 * 128; i += 256) {
    const int n = i >> 7, k = i & 127;
    w2T[i] = (f16)w2[k * 32 + n];
  }
  for (int i = tid; i < 1024; i += 256) {
    const int d = i >> 5, c = i & 31;
    aw1T[i] = aw1[c * 32 + d];
    aw2T[i] = aw2[c * 32 + d];
  }
}

// ---- kernel 1: CNN via 32x32x16 f16 MFMA implicit-GEMM, in-register maxpool,
//      wave-local attention. 512 thr, 36.4 KB LDS -> 4 blk/CU = 32 waves/CU. ----
__global__ __launch_bounds__(NTHR, 8) void seq_kernel(
    const float* __restrict__ x,
    const f16*  __restrict__ w1T, const float* __restrict__ b1,
    const f16*  __restrict__ w2T, const float* __restrict__ b2,
    const float* __restrict__ aw1T, const float* __restrict__ ab1,
    const float* __restrict__ aw2T, const float* __restrict__ ab2,
    const float* __restrict__ aw3, const float* __restrict__ ab3,
    f16* __restrict__ se_out, float* __restrict__ sc_out)
{
  __shared__ __align__(16) f16 xs[S_BLK * LSEQ * CIN];   // 6400 f16 = 12800 B
  __shared__ __align__(16) f16 h1[R1 * H1S];             // 10656 f16 = 21312 B
  __shared__ float pt[T2C][2][DCH];                      // 2304 B segmented-max partials

  const int tid  = threadIdx.x;
  const int lane = tid & 63;
  const int wave = tid >> 6;     // 0..7
  const int m    = lane & 31;    // MFMA row (A) / col (C,D) index
  const int half = lane >> 5;    // MFMA k-half selector
  const int seq0 = blockIdx.x * S_BLK;

  // ---- B fragments from pre-transposed f16 weights: 13 x 16B loads ----
  f16x8 bf1[5], bf2[8];
  {
    const f16x8* w1t8 = (const f16x8*)w1T;
    const f16x8* w2t8 = (const f16x8*)w2T;
    #pragma unroll
    for (int kc = 0; kc < 5; kc++) bf1[kc] = w1t8[m * 10 + kc * 2 + half];
    #pragma unroll
    for (int kc = 0; kc < 8; kc++) bf2[kc] = w2t8[m * 16 + kc * 2 + half];
  }
  const float b1v = b1[m], b2v = b2[m];

  // ---- stage x -> LDS f16, flat copy ----
  {
    const float4* xg = (const float4*)(x + (size_t)blockIdx.x * (S_BLK * LSEQ * CIN));
    for (int i = tid; i < S_BLK * LSEQ * CIN / 4; i += NTHR) {   // 1600 float4
      const float4 v = xg[i];
      f16x4 h; h[0] = (f16)v.x; h[1] = (f16)v.y; h[2] = (f16)v.z; h[3] = (f16)v.w;
      *(f16x4*)&xs[i * 4] = h;
    }
  }
  __syncthreads();

  // ---- conv1: M=296 N=32 K=80 ----
  for (int tile = wave; tile < T1C; tile += 8) {
    const unsigned r  = tile * 32 + m;
    const unsigned rc = (r < R1) ? r : (R1 - 1);
    const unsigned s  = rc / L1, l = rc - s * L1;
    const f16* arow = &xs[(s * LSEQ + l) * CIN];
    f32x16 acc;
    #pragma unroll
    for (int i = 0; i < 16; i++) acc[i] = b1v;
    #pragma unroll
    for (int kc = 0; kc < 5; kc++) {
      const int e = kc * 16 + half * 8;
      const f16x4 p0 = *(const f16x4*)(arow + e);
      const f16x4 p1 = *(const f16x4*)(arow + e + 4);
      const f16x8 a = __builtin_shufflevector(p0, p1, 0, 1, 2, 3, 4, 5, 6, 7);
      acc = __builtin_amdgcn_mfma_f32_32x32x16_f16(a, bf1[kc], acc, 0, 0, 0);
    }
    #pragma unroll
    for (int reg = 0; reg < 16; reg++) {
      const int rr = tile * 32 + (reg & 3) + 8 * (reg >> 2) + 4 * half;
      if (rr < R1) h1[rr * H1S + m] = (f16)selu_f(acc[reg]);
    }
  }
  __syncthreads();

  // ---- conv2: M=272 N=32 K=128, maxpool folded into the epilogue ----
  // (selu deferred: selu(max) == max(selu), SELU monotone)
  for (int tile = wave; tile < T2C; tile += 8) {
    const unsigned r  = tile * 32 + m;
    const unsigned rc = (r < R2) ? r : (R2 - 1);
    const unsigned s  = rc / L2, l = rc - s * L2;
    const f16* abase = &h1[(s * L1 + l) * H1S];
    f32x16 acc;
    #pragma unroll
    for (int i = 0; i < 16; i++) acc[i] = b2v;
    #pragma unroll
    for (int kc = 0; kc < 8; kc++) {
      const int e = (kc >> 1) * H1S + (kc & 1) * 16 + half * 8;
      const f16x4 p0 = *(const f16x4*)(abase + e);
      const f16x4 p1 = *(const f16x4*)(abase + e + 4);
      const f16x8 a = __builtin_shufflevector(p0, p1, 0, 1, 2, 3, 4, 5, 6, 7);
      acc = __builtin_amdgcn_mfma_f32_32x32x16_f16(a, bf2[kc], acc, 0, 0, 0);
    }
    // segmented max over this tile's 32 rows: a 32-row tile spans <=2 seqs.
    // exact div by 34 for rr<~300: s = (rr*241)>>13
    const int s0  = (tile * 32 * 241) >> 13;
    const int bnd = (s0 + 1) * L2;
    float mx0 = -3.4e38f, mx1 = -3.4e38f;
    #pragma unroll
    for (int reg = 0; reg < 16; reg++) {
      int rr = tile * 32 + (reg & 3) + 8 * (reg >> 2) + 4 * half;
      if (rr > R2 - 1) rr = R2 - 1;   // clamped rows duplicate row R2-1 (harmless for max)
      if (rr < bnd) mx0 = fmaxf(mx0, acc[reg]);
      else          mx1 = fmaxf(mx1, acc[reg]);
    }
    mx0 = fmaxf(mx0, __shfl_xor(mx0, 32, 64));   // combine k-halves (rows +4)
    mx1 = fmaxf(mx1, __shfl_xor(mx1, 32, 64));
    if (half == 0) { pt[tile][0][m] = mx0; pt[tile][1][m] = mx1; }
  }
  __syncthreads();

  // ---- phase D: per-(seq,channel) epilogue + attention MLP, waves 0..3, no barriers ----
  if (tid < S_BLK * DCH) {
    const int s = tid >> 5, d = tid & 31;
    // each seq's 34 rows span exactly 2 row-tiles
    const int tA = (s * L2) >> 5;
    const int tB = (s * L2 + L2 - 1) >> 5;
    const int sA = ((tA << 5) * 241) >> 13;
    const int sB = ((tB << 5) * 241) >> 13;
    const float mx = fmaxf(pt[tA][(s == sA) ? 0 : 1][d],
                           pt[tB][(s == sB) ? 0 : 1][d]);
    const float sv = selu_f(mx);
    se_out[(size_t)seq0 * DCH + tid] = (f16)sv;

    // attention layer 1: seq s lives in this 32-lane group -> shfl broadcast
    const float4* wt1 = (const float4*)aw1T;
    float a = ab1[d];
    #pragma unroll
    for (int c4 = 0; c4 < 8; c4++) {
      const float4 w = wt1[d * 8 + c4];
      a = fmaf(__shfl(sv, c4 * 4 + 0, 32), w.x, a);
      a = fmaf(__shfl(sv, c4 * 4 + 1, 32), w.y, a);
      a = fmaf(__shfl(sv, c4 * 4 + 2, 32), w.z, a);
      a = fmaf(__shfl(sv, c4 * 4 + 3, 32), w.w, a);
    }
    const float av = selu_f(a);

    // attention layer 2 + score
    const float4* wt2 = (const float4*)aw2T;
    float a2 = ab2[d];
    #pragma unroll
    for (int c4 = 0; c4 < 8; c4++) {
      const float4 w = wt2[d * 8 + c4];
      a2 = fmaf(__shfl(av, c4 * 4 + 0, 32), w.x, a2);
      a2 = fmaf(__shfl(av, c4 * 4 + 1, 32), w.y, a2);
      a2 = fmaf(__shfl(av, c4 * 4 + 2, 32), w.z, a2);
      a2 = fmaf(__shfl(av, c4 * 4 + 3, 32), w.w, a2);
    }
    float p = selu_f(a2) * aw3[d];
    #pragma unroll
    for (int off = 16; off > 0; off >>= 1) p += __shfl_xor(p, off, 32);
    if (d == 0) sc_out[seq0 + s] = p + ab3[0];
  }
}

// ---- kernel 2: per-bag softmax pooling + output MLPs (se f16) ----
__global__ __launch_bounds__(256) void bag_kernel(
    const f16* __restrict__ se, const float* __restrict__ sc,
    const float* __restrict__ aw1, const float* __restrict__ ab1,
    const float* __restrict__ aw2, const float* __restrict__ ab2,
    const float* __restrict__ bw1, const float* __restrict__ bb1,
    const float* __restrict__ bw2, const float* __restrict__ bb2,
    float* __restrict__ out)
{
  const int bag = blockIdx.x, tid = threadIdx.x;
  const size_t base = (size_t)bag * SPB;

  __shared__ float pr[4][33];
  __shared__ float red[33];
  __shared__ float pool[DCH], hA[DCH], hB[DCH];

  float m = -3.4e38f;
  for (int i = tid; i < SPB; i += 256) m = fmaxf(m, sc[base + i]);
  #pragma unroll
  for (int off = 32; off > 0; off >>= 1) m = fmaxf(m, __shfl_xor(m, off, 64));
  if ((tid & 63) == 0) pr[tid >> 6][0] = m;
  __syncthreads();
  const float bagmax = fmaxf(fmaxf(pr[0][0], pr[1][0]), fmaxf(pr[2][0], pr[3][0]));
  __syncthreads();

  float acc[33];
  #pragma unroll
  for (int d = 0; d < 33; d++) acc[d] = 0.0f;
  for (int i = tid; i < SPB; i += 256) {
    const float e = __expf(sc[base + i] - bagmax);
    acc[32] += e;
    const f16* sr = &se[(base + i) * DCH];
    #pragma unroll
    for (int q = 0; q < 8; q++) {
      const f16x4 v = *(const f16x4*)(sr + q * 4);
      #pragma unroll
      for (int j = 0; j < 4; j++) acc[q * 4 + j] = fmaf(e, (float)v[j], acc[q * 4 + j]);
    }
  }
  #pragma unroll
  for (int d = 0; d < 33; d++) {
    float v = acc[d];
    #pragma unroll
    for (int off = 32; off > 0; off >>= 1) v += __shfl_xor(v, off, 64);
    if ((tid & 63) == 0) pr[tid >> 6][d] = v;
  }
  __syncthreads();
  if (tid < 33) red[tid] = pr[0][tid] + pr[1][tid] + pr[2][tid] + pr[3][tid];
  __syncthreads();
  if (tid < DCH) pool[tid] = red[tid] / red[32];
  __syncthreads();

  if (tid < DCH) {
    float a = ab1[tid], b = bb1[tid];
    #pragma unroll
    for (int c = 0; c < DCH; c++) {
      a = fmaf(pool[c], aw1[c * DCH + tid], a);
      b = fmaf(pool[c], bw1[c * DCH + tid], b);
    }
    hA[tid] = selu_f(a);
    hB[tid] = selu_f(b);
  }
  __syncthreads();

  if (tid < 21) {
    float v = ab2[tid];
    #pragma unroll
    for (int d = 0; d < DCH; d++) v = fmaf(hA[d], aw2[d * 21 + tid], v);
    out[bag * 21 + tid] = 1.0f / (1.0f + __expf(-v));
  } else if (tid >= 32 && tid < 72) {
    const int j = tid - 32;
    float v = bb2[j];
    #pragma unroll
    for (int d = 0; d < DCH; d++) v = fmaf(hB[d], bw2[d * 40 + j], v);
    out[N_BAGS * 21 + bag * 40 + j] = 1.0f / (1.0f + __expf(-v));
  }
}

extern "C" void kernel_launch(void* const* d_in, const int* in_sizes, int n_in,
                              void* d_out, int out_size, void* d_ws, size_t ws_size,
                              hipStream_t stream)
{
  const float* x    = (const float*)d_in[0];
  const float* c1w  = (const float*)d_in[2];
  const float* c1b  = (const float*)d_in[3];
  const float* c2w  = (const float*)d_in[4];
  const float* c2b  = (const float*)d_in[5];
  const float* aw1  = (const float*)d_in[6];
  const float* ab1  = (const float*)d_in[7];
  const float* aw2  = (const float*)d_in[8];
  const float* ab2  = (const float*)d_in[9];
  const float* aw3  = (const float*)d_in[10];
  const float* ab3  = (const float*)d_in[11];
  const float* oaw1 = (const float*)d_in[12];
  const float* oab1 = (const float*)d_in[13];
  const float* oaw2 = (const float*)d_in[14];
  const float* oab2 = (const float*)d_in[15];
  const float* obw1 = (const float*)d_in[16];
  const float* obb1 = (const float*)d_in[17];
  const float* obw2 = (const float*)d_in[18];
  const float* obb2 = (const float*)d_in[19];
  float* out = (float*)d_out;

  // ws layout: seh f16 (16 MB) | sc f32 (1 MB) | w1T/w2T f16 | aw1T/aw2T f32
  char* ws = (char*)d_ws;
  f16*   seh  = (f16*)ws;                                   // 8,000,000 f16
  float* sc   = (float*)(ws + (size_t)16000000);            // 250,000 f32
  f16*   w1T  = (f16*)(ws + (size_t)17000000);              // 2560 f16
  f16*   w2T  = w1T + 2560 + 2560;                          // 16B-aligned; 4096 f16
  float* aw1T = (float*)(ws + (size_t)17000000 + 32768);    // 1024 f32
  float* aw2T = aw1T + 1024;

  prep_kernel<<<1, 256, 0, stream>>>(c1w, c2w, aw1, aw2, w1T, w2T, aw1T, aw2T);
  seq_kernel<<<N_SEQ / S_BLK, NTHR, 0, stream>>>(x, w1T, c1b, w2T, c2b,
                                                 aw1T, ab1, aw2T, ab2, aw3, ab3,
                                                 seh, sc);
  bag_kernel<<<N_BAGS, 256, 0, stream>>>(seh, sc, oaw1, oab1, oaw2, oab2,
                                         obw1, obb1, obw2, obb2, out);
}

// Round 2
// 1440.610 us; speedup vs baseline: 1.4747x; 1.4747x over previous
//
#include <hip/hip_runtime.h>

#define N_SEQ 250000
#define LSEQ  40
#define CIN   20
#define KW    4
#define DCH   32
#define L1    37   // LSEQ - KW + 1
#define L2    34   // L1 - KW + 1
#define N_BAGS 100
#define SPB   2500
#define S_BLK 4
#define NTHR  256
#define R1    (S_BLK * L1)   // 148 conv1 output rows / block
#define R2    (S_BLK * L2)   // 136 conv2 output rows / block
#define T1C   5              // ceil(148/32) tiles of 32 rows
#define T2C   5              // ceil(136/32)
#define H1S   36             // h1 LDS row stride (f16): 72 B -> b64 reads land 2-way-free banks

typedef _Float16 f16;
typedef _Float16 f16x8 __attribute__((ext_vector_type(8)));
typedef _Float16 f16x4 __attribute__((ext_vector_type(4)));
typedef float    f32x16 __attribute__((ext_vector_type(16)));

__device__ __forceinline__ float selu_f(float x) {
  float e = 1.6732632423543772f * (__expf(x) - 1.0f);
  return 1.0507009873554805f * ((x > 0.0f) ? x : e);
}

// ---- prep: transpose+convert weights once per launch (1 block, ~2 us) ----
__global__ __launch_bounds__(256) void prep_kernel(
    const float* __restrict__ w1, const float* __restrict__ w2,
    const float* __restrict__ aw1, const float* __restrict__ aw2,
    f16* __restrict__ w1T, f16* __restrict__ w2T,
    float* __restrict__ aw1T, float* __restrict__ aw2T)
{
  const int tid = threadIdx.x;
  for (int i = tid; i < 32 * 80; i += 256) {
    const int n = i / 80, k = i - n * 80;
    w1T[i] = (f16)w1[k * 32 + n];
  }
  for (int i = tid; i < 32 * 128; i += 256) {
    const int n = i >> 7, k = i & 127;
    w2T[i] = (f16)w2[k * 32 + n];
  }
  for (int i = tid; i < 1024; i += 256) {
    const int d = i >> 5, c = i & 31;
    aw1T[i] = aw1[c * 32 + d];
    aw2T[i] = aw2[c * 32 + d];
  }
}

// ---- kernel 1: CNN via 32x32x16 f16 MFMA implicit-GEMM, in-register maxpool,
//      wave-local attention. 256 thr, ~18.4 KB LDS -> 8 blk/CU = 32 waves/CU.
//      launch_bounds(256,4): VGPR cap 128 (round-0-proven; NEVER cap at 64 —
//      round 1's (512,8) forced 32 VGPR and spilled 2.4 GB to scratch). ----
__global__ __launch_bounds__(NTHR, 4) void seq_kernel(
    const float* __restrict__ x,
    const f16*  __restrict__ w1T, const float* __restrict__ b1,
    const f16*  __restrict__ w2T, const float* __restrict__ b2,
    const float* __restrict__ aw1T, const float* __restrict__ ab1,
    const float* __restrict__ aw2T, const float* __restrict__ ab2,
    const float* __restrict__ aw3, const float* __restrict__ ab3,
    f16* __restrict__ se_out, float* __restrict__ sc_out)
{
  __shared__ __align__(16) f16 xs[S_BLK * LSEQ * CIN];   // 3200 f16 = 6400 B
  __shared__ __align__(16) f16 h1[R1 * H1S];             // 5328 f16 = 10656 B
  __shared__ float pt[T2C][2][DCH];                      // 1280 B segmented-max partials

  const int tid  = threadIdx.x;
  const int lane = tid & 63;
  const int wave = tid >> 6;     // 0..3
  const int m    = lane & 31;    // MFMA row (A) / col (C,D) index
  const int half = lane >> 5;    // MFMA k-half selector
  const int seq0 = blockIdx.x * S_BLK;

  // ---- stage x -> LDS f16, flat copy ----
  {
    const float4* xg = (const float4*)(x + (size_t)blockIdx.x * (S_BLK * LSEQ * CIN));
    for (int i = tid; i < S_BLK * LSEQ * CIN / 4; i += NTHR) {   // 800 float4
      const float4 v = xg[i];
      f16x4 h; h[0] = (f16)v.x; h[1] = (f16)v.y; h[2] = (f16)v.z; h[3] = (f16)v.w;
      *(f16x4*)&xs[i * 4] = h;
    }
  }

  // ---- conv1 B fragments (load while staging is in flight) ----
  f16x8 bf1[5];
  {
    const f16x8* w1t8 = (const f16x8*)w1T;
    #pragma unroll
    for (int kc = 0; kc < 5; kc++) bf1[kc] = w1t8[m * 10 + kc * 2 + half];
  }
  const float b1v = b1[m];
  __syncthreads();

  // ---- conv1: M=148 N=32 K=80 ----
  for (int tile = wave; tile < T1C; tile += 4) {
    const unsigned r  = tile * 32 + m;
    const unsigned rc = (r < R1) ? r : (R1 - 1);
    const unsigned s  = rc / L1, l = rc - s * L1;
    const f16* arow = &xs[(s * LSEQ + l) * CIN];
    f32x16 acc;
    #pragma unroll
    for (int i = 0; i < 16; i++) acc[i] = b1v;
    #pragma unroll
    for (int kc = 0; kc < 5; kc++) {
      const int e = kc * 16 + half * 8;
      const f16x4 p0 = *(const f16x4*)(arow + e);
      const f16x4 p1 = *(const f16x4*)(arow + e + 4);
      const f16x8 a = __builtin_shufflevector(p0, p1, 0, 1, 2, 3, 4, 5, 6, 7);
      acc = __builtin_amdgcn_mfma_f32_32x32x16_f16(a, bf1[kc], acc, 0, 0, 0);
    }
    #pragma unroll
    for (int reg = 0; reg < 16; reg++) {
      const int rr = tile * 32 + (reg & 3) + 8 * (reg >> 2) + 4 * half;
      if (rr < R1) h1[rr * H1S + m] = (f16)selu_f(acc[reg]);
    }
  }

  // ---- conv2 B fragments (short live range: loaded only after conv1) ----
  f16x8 bf2[8];
  {
    const f16x8* w2t8 = (const f16x8*)w2T;
    #pragma unroll
    for (int kc = 0; kc < 8; kc++) bf2[kc] = w2t8[m * 16 + kc * 2 + half];
  }
  const float b2v = b2[m];
  __syncthreads();

  // ---- conv2: M=136 N=32 K=128, maxpool folded into the epilogue ----
  // (selu deferred: selu(max) == max(selu), SELU monotone)
  for (int tile = wave; tile < T2C; tile += 4) {
    const unsigned r  = tile * 32 + m;
    const unsigned rc = (r < R2) ? r : (R2 - 1);
    const unsigned s  = rc / L2, l = rc - s * L2;
    const f16* abase = &h1[(s * L1 + l) * H1S];
    f32x16 acc;
    #pragma unroll
    for (int i = 0; i < 16; i++) acc[i] = b2v;
    #pragma unroll
    for (int kc = 0; kc < 8; kc++) {
      const int e = (kc >> 1) * H1S + (kc & 1) * 16 + half * 8;
      const f16x4 p0 = *(const f16x4*)(abase + e);
      const f16x4 p1 = *(const f16x4*)(abase + e + 4);
      const f16x8 a = __builtin_shufflevector(p0, p1, 0, 1, 2, 3, 4, 5, 6, 7);
      acc = __builtin_amdgcn_mfma_f32_32x32x16_f16(a, bf2[kc], acc, 0, 0, 0);
    }
    // segmented max over this tile's 32 rows: a 32-row tile spans <=2 seqs.
    // exact div by 34 for rr < ~300: s = (rr*241)>>13
    const int s0  = (tile * 32 * 241) >> 13;
    const int bnd = (s0 + 1) * L2;
    float mx0 = -3.4e38f, mx1 = -3.4e38f;
    #pragma unroll
    for (int reg = 0; reg < 16; reg++) {
      int rr = tile * 32 + (reg & 3) + 8 * (reg >> 2) + 4 * half;
      if (rr > R2 - 1) rr = R2 - 1;   // clamped rows duplicate row R2-1 (harmless for max)
      if (rr < bnd) mx0 = fmaxf(mx0, acc[reg]);
      else          mx1 = fmaxf(mx1, acc[reg]);
    }
    mx0 = fmaxf(mx0, __shfl_xor(mx0, 32, 64));   // combine k-halves (rows +4)
    mx1 = fmaxf(mx1, __shfl_xor(mx1, 32, 64));
    if (half == 0) { pt[tile][0][m] = mx0; pt[tile][1][m] = mx1; }
  }
  __syncthreads();

  // ---- phase D: per-(seq,channel) epilogue + attention MLP, waves 0..1, no barriers ----
  if (tid < S_BLK * DCH) {
    const int s = tid >> 5, d = tid & 31;
    // each seq's 34 rows span exactly 2 row-tiles
    const int tA = (s * L2) >> 5;
    const int tB = (s * L2 + L2 - 1) >> 5;
    const int sA = ((tA << 5) * 241) >> 13;
    const int sB = ((tB << 5) * 241) >> 13;
    const float mx = fmaxf(pt[tA][(s == sA) ? 0 : 1][d],
                           pt[tB][(s == sB) ? 0 : 1][d]);
    const float sv = selu_f(mx);
    se_out[(size_t)seq0 * DCH + tid] = (f16)sv;

    // attention layer 1: seq s lives in this 32-lane group -> shfl broadcast
    const float4* wt1 = (const float4*)aw1T;
    float a = ab1[d];
    #pragma unroll
    for (int c4 = 0; c4 < 8; c4++) {
      const float4 w = wt1[d * 8 + c4];
      a = fmaf(__shfl(sv, c4 * 4 + 0, 32), w.x, a);
      a = fmaf(__shfl(sv, c4 * 4 + 1, 32), w.y, a);
      a = fmaf(__shfl(sv, c4 * 4 + 2, 32), w.z, a);
      a = fmaf(__shfl(sv, c4 * 4 + 3, 32), w.w, a);
    }
    const float av = selu_f(a);

    // attention layer 2 + score
    const float4* wt2 = (const float4*)aw2T;
    float a2 = ab2[d];
    #pragma unroll
    for (int c4 = 0; c4 < 8; c4++) {
      const float4 w = wt2[d * 8 + c4];
      a2 = fmaf(__shfl(av, c4 * 4 + 0, 32), w.x, a2);
      a2 = fmaf(__shfl(av, c4 * 4 + 1, 32), w.y, a2);
      a2 = fmaf(__shfl(av, c4 * 4 + 2, 32), w.z, a2);
      a2 = fmaf(__shfl(av, c4 * 4 + 3, 32), w.w, a2);
    }
    float p = selu_f(a2) * aw3[d];
    #pragma unroll
    for (int off = 16; off > 0; off >>= 1) p += __shfl_xor(p, off, 32);
    if (d == 0) sc_out[seq0 + s] = p + ab3[0];
  }
}

// ---- kernel 2: per-bag softmax pooling + output MLPs (se f16) ----
__global__ __launch_bounds__(256) void bag_kernel(
    const f16* __restrict__ se, const float* __restrict__ sc,
    const float* __restrict__ aw1, const float* __restrict__ ab1,
    const float* __restrict__ aw2, const float* __restrict__ ab2,
    const float* __restrict__ bw1, const float* __restrict__ bb1,
    const float* __restrict__ bw2, const float* __restrict__ bb2,
    float* __restrict__ out)
{
  const int bag = blockIdx.x, tid = threadIdx.x;
  const size_t base = (size_t)bag * SPB;

  __shared__ float pr[4][33];
  __shared__ float red[33];
  __shared__ float pool[DCH], hA[DCH], hB[DCH];

  float m = -3.4e38f;
  for (int i = tid; i < SPB; i += 256) m = fmaxf(m, sc[base + i]);
  #pragma unroll
  for (int off = 32; off > 0; off >>= 1) m = fmaxf(m, __shfl_xor(m, off, 64));
  if ((tid & 63) == 0) pr[tid >> 6][0] = m;
  __syncthreads();
  const float bagmax = fmaxf(fmaxf(pr[0][0], pr[1][0]), fmaxf(pr[2][0], pr[3][0]));
  __syncthreads();

  float acc[33];
  #pragma unroll
  for (int d = 0; d < 33; d++) acc[d] = 0.0f;
  for (int i = tid; i < SPB; i += 256) {
    const float e = __expf(sc[base + i] - bagmax);
    acc[32] += e;
    const f16* sr = &se[(base + i) * DCH];
    #pragma unroll
    for (int q = 0; q < 8; q++) {
      const f16x4 v = *(const f16x4*)(sr + q * 4);
      #pragma unroll
      for (int j = 0; j < 4; j++) acc[q * 4 + j] = fmaf(e, (float)v[j], acc[q * 4 + j]);
    }
  }
  #pragma unroll
  for (int d = 0; d < 33; d++) {
    float v = acc[d];
    #pragma unroll
    for (int off = 32; off > 0; off >>= 1) v += __shfl_xor(v, off, 64);
    if ((tid & 63) == 0) pr[tid >> 6][d] = v;
  }
  __syncthreads();
  if (tid < 33) red[tid] = pr[0][tid] + pr[1][tid] + pr[2][tid] + pr[3][tid];
  __syncthreads();
  if (tid < DCH) pool[tid] = red[tid] / red[32];
  __syncthreads();

  if (tid < DCH) {
    float a = ab1[tid], b = bb1[tid];
    #pragma unroll
    for (int c = 0; c < DCH; c++) {
      a = fmaf(pool[c], aw1[c * DCH + tid], a);
      b = fmaf(pool[c], bw1[c * DCH + tid], b);
    }
    hA[tid] = selu_f(a);
    hB[tid] = selu_f(b);
  }
  __syncthreads();

  if (tid < 21) {
    float v = ab2[tid];
    #pragma unroll
    for (int d = 0; d < DCH; d++) v = fmaf(hA[d], aw2[d * 21 + tid], v);
    out[bag * 21 + tid] = 1.0f / (1.0f + __expf(-v));
  } else if (tid >= 32 && tid < 72) {
    const int j = tid - 32;
    float v = bb2[j];
    #pragma unroll
    for (int d = 0; d < DCH; d++) v = fmaf(hB[d], bw2[d * 40 + j], v);
    out[N_BAGS * 21 + bag * 40 + j] = 1.0f / (1.0f + __expf(-v));
  }
}

extern "C" void kernel_launch(void* const* d_in, const int* in_sizes, int n_in,
                              void* d_out, int out_size, void* d_ws, size_t ws_size,
                              hipStream_t stream)
{
  const float* x    = (const float*)d_in[0];
  const float* c1w  = (const float*)d_in[2];
  const float* c1b  = (const float*)d_in[3];
  const float* c2w  = (const float*)d_in[4];
  const float* c2b  = (const float*)d_in[5];
  const float* aw1  = (const float*)d_in[6];
  const float* ab1  = (const float*)d_in[7];
  const float* aw2  = (const float*)d_in[8];
  const float* ab2  = (const float*)d_in[9];
  const float* aw3  = (const float*)d_in[10];
  const float* ab3  = (const float*)d_in[11];
  const float* oaw1 = (const float*)d_in[12];
  const float* oab1 = (const float*)d_in[13];
  const float* oaw2 = (const float*)d_in[14];
  const float* oab2 = (const float*)d_in[15];
  const float* obw1 = (const float*)d_in[16];
  const float* obb1 = (const float*)d_in[17];
  const float* obw2 = (const float*)d_in[18];
  const float* obb2 = (const float*)d_in[19];
  float* out = (float*)d_out;

  // ws layout: seh f16 (16 MB) | sc f32 (1 MB) | w1T/w2T f16 | aw1T/aw2T f32
  char* ws = (char*)d_ws;
  f16*   seh  = (f16*)ws;                                   // 8,000,000 f16
  float* sc   = (float*)(ws + (size_t)16000000);            // 250,000 f32
  f16*   w1T  = (f16*)(ws + (size_t)17000000);              // 2560 f16
  f16*   w2T  = w1T + 2560 + 2560;                          // 16B-aligned; 4096 f16
  float* aw1T = (float*)(ws + (size_t)17000000 + 32768);    // 1024 f32
  float* aw2T = aw1T + 1024;

  prep_kernel<<<1, 256, 0, stream>>>(c1w, c2w, aw1, aw2, w1T, w2T, aw1T, aw2T);
  seq_kernel<<<N_SEQ / S_BLK, NTHR, 0, stream>>>(x, w1T, c1b, w2T, c2b,
                                                 aw1T, ab1, aw2T, ab2, aw3, ab3,
                                                 seh, sc);
  bag_kernel<<<N_BAGS, 256, 0, stream>>>(seh, sc, oaw1, oab1, oaw2, oab2,
                                         obw1, obb1, obw2, obb2, out);
}